// Round 3
// baseline (964.988 us; speedup 1.0000x reference)
//
#include <hip/hip_runtime.h>
#include <hip/hip_bf16.h>
#include <hip/hip_cooperative_groups.h>
namespace cg = cooperative_groups;

// Model: one_hot -> 3x Conv2D(5,(4,4),(1,2),SAME) -> [B,S=1024,D=20]
//        -> 3x causal self-attention -> flatten -> 3x Dense(10)
// B=64, L=8192, S=1024, D=20.
// R19 (216us): 6 launches, fused attn strips, balanced swizzle.
// R20 (267us): de-staged K+V -> latency-bound. R21 (228us): t-split + combine
//      kernels -> per-kernel cost small but 10 launches; totals say ~10-15us
//      PER-LAUNCH overhead dominates (sum of kernel work ~70us vs 228 total).
// R22: ONE cooperative mega-kernel. grid.sync() between phases replaces all
//      inter-kernel gaps. Attn phases = R19's proven staged structure.
//      grid=1024 (4 blocks/CU guaranteed via __launch_bounds__(256,4), LDS
//      34.3KB*4=137KB<=160KB). Same-CU blocks {i,i+256,i+512,i+768} share b
//      (K/V in L1) with strips {r,7-r,8+r,15-r} -> tile-weight 18/CU const;
//      blk%8==b%8 -> XCD b-locality. Convs restructured pos-by-pos to fit the
//      128-VGPR cap (fp32 reassociation only). Fallback: plain 6-launch path
//      if cooperative launch is rejected.

#define B_ 64
#define L_ 8192
#define S_ 1024
#define D_ 20
#define SMEM_BYTES 34304   // attn !FUSE phase: 10240(kts)+8704(vts)+15360(red)

typedef unsigned short ushort_t;
typedef __attribute__((ext_vector_type(8))) short short8_t;  // 8 bf16 (4 VGPRs)
typedef __attribute__((ext_vector_type(4))) short short4_t;  // 4 bf16 (2 VGPRs)
typedef __attribute__((ext_vector_type(4))) float f32x4_t;   // MFMA C/D

__device__ __forceinline__ ushort_t f2bf(float f) {          // RNE fp32->bf16
  unsigned u = __float_as_uint(f);
  return (ushort_t)((u + 0x7fffu + ((u >> 16) & 1u)) >> 16);
}
__device__ __forceinline__ float bf2f(ushort_t h) {
  return __uint_as_float(((unsigned)h) << 16);
}

// ---------------- phase 0: fused conv1+conv2 (+ W1 transpose tail) --------
__device__ __forceinline__ void conv12_body(
    char* smemc, const int blk, const int tid, const int nblocks,
    const int* __restrict__ inp,
    const float* __restrict__ W1c, const float* __restrict__ B1c,
    const float* __restrict__ W2c, const float* __restrict__ B2c,
    float* __restrict__ out,                      // c2 [B,4,2048,5]
    const float* __restrict__ W1d,                // dense W1 [20480,10]
    float* __restrict__ W1T) {                    // [10,20480]
  if (blk < 512) {
    float* w1s = (float*)smemc;        // 80
    float* b1s = w1s + 80;             // 5
    float* w2s = w1s + 88;             // 400
    float* b2s = w1s + 488;            // 5
    for (int j = tid; j < 400; j += 256) w2s[j] = W2c[j];
    if (tid < 80)      w1s[tid]      = W1c[tid];
    else if (tid < 85) b1s[tid - 80] = B1c[tid - 80];
    else if (tid < 90) b2s[tid - 85] = B2c[tid - 85];
    __syncthreads();
    const int idx = blk * 256 + tid;   // 131072 total
    const int b  = idx >> 11;
    const int wo = idx & 2047;
    const int* ib = inp + (size_t)b * L_;
    int iv[10];
#pragma unroll
    for (int t = 0; t < 10; ++t) {
      int g = 4 * wo - 3 + t;
      iv[t] = (g >= 0 && g < L_) ? ib[g] : -100; // sentinel: no kh matches
    }
    float acc[4][5];
#pragma unroll
    for (int h = 0; h < 4; ++h)
#pragma unroll
      for (int c = 0; c < 5; ++c) acc[h][c] = b2s[c];
    // pos-by-pos: vp live range 20 floats instead of 80 (VGPR cap 128)
#pragma unroll
    for (int pos = 0; pos < 4; ++pos) {
      float vp[4][5];
      const int w1 = 2 * wo - 1 + pos;
      const bool okp = (w1 >= 0 && w1 < 4096);   // conv2 SAME padding -> 0
#pragma unroll
      for (int hi = 0; hi < 4; ++hi)
#pragma unroll
        for (int ci = 0; ci < 5; ++ci) vp[hi][ci] = okp ? b1s[ci] : 0.f;
      if (okp) {
#pragma unroll
        for (int kw = 0; kw < 4; ++kw) {
          const int gw = 2 * w1 - 1 + kw;
          if (gw >= 0 && gw < L_) {
            const int v = iv[2 * pos + kw];
#pragma unroll
            for (int hi = 0; hi < 4; ++hi) {
              const int kh = v - hi + 1;
              if (kh >= 0 && kh < 4) {
#pragma unroll
                for (int ci = 0; ci < 5; ++ci)
                  vp[hi][ci] += w1s[(kh * 4 + kw) * 5 + ci];
              }
            }
          }
        }
      }
#pragma unroll
      for (int kh = 0; kh < 4; ++kh)
#pragma unroll
        for (int ci = 0; ci < 5; ++ci) {
          const float* wp = w2s + ((kh * 4 + pos) * 5 + ci) * 5;
          float w0 = wp[0], w1v = wp[1], w2v = wp[2], w3v = wp[3], w4v = wp[4];
#pragma unroll
          for (int h = 0; h < 4; ++h) {
            int hi = h - 1 + kh;
            if (hi >= 0 && hi < 4) {
              float x = vp[hi][ci];
              acc[h][0] += w0 * x;  acc[h][1] += w1v * x; acc[h][2] += w2v * x;
              acc[h][3] += w3v * x; acc[h][4] += w4v * x;
            }
          }
        }
    }
    float* ob = out + (size_t)b * 4 * 2048 * 5;
#pragma unroll
    for (int h = 0; h < 4; ++h)
#pragma unroll
      for (int c = 0; c < 5; ++c) ob[(h * 2048 + wo) * 5 + c] = acc[h][c];
  }
  // ---- tail: W1 transpose (all blocks participate) ----
  for (int j = blk * 256 + tid; j < 204800; j += nblocks * 256) {
    int col = j / 20480, i2 = j - col * 20480;
    W1T[j] = W1d[i2 * 10 + col];
  }
}

// ---------------- phase 1: fused conv3 + proj (layer 1) -------------------
__device__ __forceinline__ void conv3proj_body(
    char* smemc, const int blk, const int tid,
    const float* __restrict__ in,                 // c2 [B,4,2048,5]
    const float* __restrict__ W,  const float* __restrict__ Bi,
    const float* __restrict__ Kw, const float* __restrict__ Qw,
    const float* __restrict__ Vw,
    ushort_t* __restrict__ Qb, ushort_t* __restrict__ Kb,
    ushort_t* __restrict__ Vt) {
  if (blk >= 256) return;
  constexpr int WIN = 2048;
  float* ws  = (float*)smemc;  // 400
  float* bs  = ws + 400;       // 5 (pad to 8)
  float* kws = ws + 408;       // 400
  float* qws = ws + 808;       // 400
  float* vws = ws + 1208;      // 400
  for (int j = tid; j < 400; j += 256) {
    ws[j] = W[j]; kws[j] = Kw[j]; qws[j] = Qw[j]; vws[j] = Vw[j];
  }
  if (tid < 5) bs[tid] = Bi[tid];
  __syncthreads();
  const int r  = blk * 256 + tid;  // row in [0, 65536)
  const int b  = r >> 10;
  const int wo = r & 1023;
  float acc[4][5];
#pragma unroll
  for (int h = 0; h < 4; ++h)
#pragma unroll
    for (int c = 0; c < 5; ++c) acc[h][c] = bs[c];
#pragma unroll
  for (int kwp = 0; kwp < 4; ++kwp) {
    float vp[4][5];
    const int wi = 2 * wo - 1 + kwp;
    const bool ok = (wi >= 0 && wi < WIN);
#pragma unroll
    for (int hi = 0; hi < 4; ++hi) {
      const float* ir = in + ((size_t)b * 4 + hi) * WIN * 5;
#pragma unroll
      for (int ci = 0; ci < 5; ++ci) vp[hi][ci] = ok ? ir[wi * 5 + ci] : 0.f;
    }
#pragma unroll
    for (int kh = 0; kh < 4; ++kh)
#pragma unroll
      for (int ci = 0; ci < 5; ++ci) {
        const float* wp = ws + ((kh * 4 + kwp) * 5 + ci) * 5;
        float w0 = wp[0], w1 = wp[1], w2 = wp[2], w3 = wp[3], w4 = wp[4];
#pragma unroll
        for (int h = 0; h < 4; ++h) {
          int hi = h - 1 + kh;
          if (hi >= 0 && hi < 4) {
            float x = vp[hi][ci];
            acc[h][0] += w0 * x; acc[h][1] += w1 * x; acc[h][2] += w2 * x;
            acc[h][3] += w3 * x; acc[h][4] += w4 * x;
          }
        }
      }
  }
  float x[D_];
#pragma unroll
  for (int h = 0; h < 4; ++h)
#pragma unroll
    for (int c = 0; c < 5; ++c) x[h * 5 + c] = acc[h][c];
  float q[D_], k[D_], v[D_];
#pragma unroll
  for (int j = 0; j < D_; ++j) { q[j] = 0.f; k[j] = 0.f; v[j] = 0.f; }
#pragma unroll
  for (int i = 0; i < D_; ++i) {
#pragma unroll
    for (int j = 0; j < D_; ++j) {
      q[j] += x[i] * qws[i * D_ + j];
      k[j] += x[i] * kws[i * D_ + j];
      v[j] += x[i] * vws[i * D_ + j];
    }
  }
  const float sc = 0.22360679774997896f;  // 1/sqrt(20)
  ushort_t qt[32], kt[32];
#pragma unroll
  for (int j = 0; j < D_; ++j) { qt[j] = f2bf(q[j] * sc); kt[j] = f2bf(k[j]); }
#pragma unroll
  for (int j = D_; j < 32; ++j) { qt[j] = 0; kt[j] = 0; }
  int4* qd = (int4*)(Qb + (size_t)r * 32);
  int4* kd = (int4*)(Kb + (size_t)r * 32);
#pragma unroll
  for (int j = 0; j < 4; ++j) {
    qd[j] = *(const int4*)(qt + 8 * j);
    kd[j] = *(const int4*)(kt + 8 * j);
  }
  ushort_t* vbase = Vt + ((size_t)b * 32) * 1024 + wo;
#pragma unroll
  for (int d = 0; d < D_; ++d) vbase[d * 1024] = f2bf(v[d]);
}

// ---------------- phases 2-4: causal attention (R19 staged structure) -----
// S^T = mfma_16x16x32(Kfrag, Qfrag): lane (quad,n): S^T[t=quad*4+r][q=n].
// P^T register layout IS the B-operand of mfma_16x16x16; PV from registers.
// Block mapping: b = blk&63 (same-CU blocks share b -> K/V L1-shared;
// blk%8==b%8 -> XCD locality). raw strip = blk>>6; map {r,r+4,r+8,r+12} ->
// {r, 7-r, 8+r, 15-r}: per-CU tile weight = 18 (constant).
// FUSE=true : epilogue projects O rows -> next layer's Qb2/Kb2/Vt2.
// FUSE=false: epilogue computes dense1 partial -> part2[b][strip][10].
template <bool FUSE>
__device__ __forceinline__ void attn_body(
    char* smemc, const int blk, const int tid,
    const ushort_t* __restrict__ Qb, const ushort_t* __restrict__ Kb,
    const ushort_t* __restrict__ Vt,
    const float* __restrict__ Kw2, const float* __restrict__ Qw2,
    const float* __restrict__ Vw2,
    ushort_t* __restrict__ Qb2, ushort_t* __restrict__ Kb2,
    ushort_t* __restrict__ Vt2,
    const float* __restrict__ W1T,   // !FUSE: [10,20480]
    float* __restrict__ part2) {     // !FUSE: [64,16,10]
  const int b   = blk & 63;
  const int raw = blk >> 6;            // 0..15
  const int rr4 = raw & 3, k4 = raw >> 2;
  const int strip = (k4 == 0) ? rr4 : (k4 == 1) ? 7 - rr4
                  : (k4 == 2) ? 8 + rr4 : 15 - rr4;
  const int q0    = strip * 64;
  const int w     = tid >> 6;             // wave 0..3
  const int lane  = tid & 63;
  const int n     = lane & 15;
  const int quad  = lane >> 4;
  const int qbase = q0 + 16 * w;
  const int qg    = qbase + n;            // this lane's q column
  ushort_t* kts = (ushort_t*)smemc;             // [128*40] K tile
  ushort_t* vts = (ushort_t*)(smemc + 10240);   // [32*136] V^T tile
  float* extraf = (float*)(smemc + 18944);      // FUSE: 1200 w + 1280 ox
                                                // !FUSE: 1280 ox + 2560 red
  if constexpr (FUSE) {
    float tmp[5];
#pragma unroll
    for (int u = 0; u < 5; ++u) {
      int j = tid + u * 256;
      if (j < 1200) {
        int m = j / 400, oo = j - m * 400;
        tmp[u] = (m == 0) ? Kw2[oo] : (m == 1) ? Qw2[oo] : Vw2[oo];
      }
    }
#pragma unroll
    for (int u = 0; u < 5; ++u) {
      int j = tid + u * 256;
      if (j < 1200) extraf[j] = tmp[u];
    }
  }
  const ushort_t* KbB = Kb + (size_t)b * 1024 * 32;
  const ushort_t* VtB = Vt + (size_t)b * 32 * 1024;
  short8_t qfrag = *(const short8_t*)(Qb + ((size_t)(b * 1024 + qbase + n)) * 32 + quad * 8);
  f32x4_t oA = {0.f, 0.f, 0.f, 0.f};      // O^T[d=quad*4+r][q=n]
  f32x4_t oB = {0.f, 0.f, 0.f, 0.f};      // O^T[d=16+quad*4+r][q=n] (quad0 valid)
  float lsum = 0.f;
  const f32x4_t zero = {0.f, 0.f, 0.f, 0.f};
  const int nt = q0 + 64;                 // block-uniform staging bound
  for (int t0 = 0; t0 < nt; t0 += 128) {
    __syncthreads();
    for (int i = tid; i < 512; i += 256) {
      int row = i >> 2, qc = i & 3;
      *(int4*)(kts + row * 40 + qc * 8) =
          *(const int4*)(KbB + (size_t)(t0 + row) * 32 + qc * 8);
    }
    for (int i = tid; i < 320; i += 256) {
      int row = i >> 4, cc = i & 15;
      *(int4*)(vts + row * 136 + cc * 8) =
          *(const int4*)(VtB + (size_t)row * 1024 + t0 + cc * 8);
    }
    __syncthreads();
    // preload K A-frags for all 8 16-t blocks (no LDS dep in compute loop)
    short8_t kf[8];
#pragma unroll
    for (int hc = 0; hc < 8; ++hc)
      kf[hc] = *(const short8_t*)(kts + (hc * 16 + n) * 40 + quad * 8);
#pragma unroll
    for (int hc = 0; hc < 8; ++hc) {
      const int tg = t0 + hc * 16 + quad * 4;     // global t of r=0
      f32x4_t s = __builtin_amdgcn_mfma_f32_16x16x32_bf16(kf[hc], qfrag, zero, 0, 0, 0);
      ushort_t pk4[4];
#pragma unroll
      for (int r = 0; r < 4; ++r) {
        float p = (tg + r <= qg) ? __expf(s[r]) : 0.f;
        ushort_t h = f2bf(p);
        lsum += bf2f(h);                  // consistent with bf16 P used in PV
        pk4[r] = h;
      }
      short4_t pfrag = *(const short4_t*)pk4;     // B16-frag: k=quad*4+j, n=q
      short4_t vlo = *(const short4_t*)(vts + n * 136 + hc * 16 + quad * 4);
      short4_t vhi = *(const short4_t*)(vts + (16 + n) * 136 + hc * 16 + quad * 4);
      oA = __builtin_amdgcn_mfma_f32_16x16x16bf16_1k(vlo, pfrag, oA, 0, 0, 0);
      oB = __builtin_amdgcn_mfma_f32_16x16x16bf16_1k(vhi, pfrag, oB, 0, 0, 0);
    }
  }
  // l[q=n]: reduce partial sums across the 4 quads
  float l = lsum;
  l += __shfl_xor(l, 16, 64);
  l += __shfl_xor(l, 32, 64);
  const float inv = 1.f / l;
  if constexpr (FUSE) {
    float* pw  = extraf;
    float* oxw = extraf + 1200 + w * 320;
#pragma unroll
    for (int r = 0; r < 4; ++r) oxw[n * 20 + quad * 4 + r] = oA[r] * inv;
    if (quad == 0) {
#pragma unroll
      for (int r = 0; r < 4; ++r) oxw[n * 20 + 16 + r] = oB[r] * inv;
    }
    __asm__ volatile("s_waitcnt lgkmcnt(0)" ::: "memory");  // wave-sync LDS RAW
    const int row  = lane >> 2;     // 0..15
    const int part = lane & 3;      // cols 5*part .. 5*part+4
    float x[D_];
#pragma unroll
    for (int i = 0; i < D_; ++i) x[i] = oxw[row * 20 + i];
    float qv[5], kv[5], vv[5];
#pragma unroll
    for (int jj = 0; jj < 5; ++jj) { qv[jj] = 0.f; kv[jj] = 0.f; vv[jj] = 0.f; }
#pragma unroll
    for (int i = 0; i < D_; ++i) {
      const float xi = x[i];
#pragma unroll
      for (int jj = 0; jj < 5; ++jj) {
        const int j = 5 * part + jj;
        kv[jj] += xi * pw[i * 20 + j];          // K block
        qv[jj] += xi * pw[400 + i * 20 + j];    // Q block
        vv[jj] += xi * pw[800 + i * 20 + j];    // V block
      }
    }
    const float sc = 0.22360679774997896f;
    const int rg = b * 1024 + qbase + row;
    const int s  = rg & 1023;
#pragma unroll
    for (int jj = 0; jj < 5; ++jj) {
      const int j = 5 * part + jj;
      Kb2[(size_t)rg * 32 + j] = f2bf(kv[jj]);
      Qb2[(size_t)rg * 32 + j] = f2bf(qv[jj] * sc);
      Vt2[(size_t)b * 32768 + (size_t)j * 1024 + s] = f2bf(vv[jj]);
    }
    if (part == 0) {
#pragma unroll
      for (int u = 0; u < 6; ++u)
        *(unsigned*)(Kb2 + (size_t)rg * 32 + 20 + 2 * u) = 0u;
    } else if (part == 1) {
#pragma unroll
      for (int u = 0; u < 6; ++u)
        *(unsigned*)(Qb2 + (size_t)rg * 32 + 20 + 2 * u) = 0u;
    }
  } else {
    // ---- fused dense1 partial over this block's 64 rows ----
    float* oxflat = extraf;              // [1280]
    float* oxw    = oxflat + w * 320;
    float* red    = extraf + 1280;       // [256][10]
#pragma unroll
    for (int r = 0; r < 4; ++r) oxw[n * 20 + quad * 4 + r] = oA[r] * inv;
    if (quad == 0) {
#pragma unroll
      for (int r = 0; r < 4; ++r) oxw[n * 20 + 16 + r] = oB[r] * inv;
    }
    __syncthreads();                     // all waves' ox visible
    float acc[10];
#pragma unroll
    for (int j = 0; j < 10; ++j) acc[j] = 0.f;
    const float* wb = W1T;               // [10][20480]
    const int base = q0 * 20;
#pragma unroll
    for (int k = 0; k < 5; ++k) {
      const int il = tid + 256 * k;
      const float xv = oxflat[il];
#pragma unroll
      for (int j = 0; j < 10; ++j)
        acc[j] += xv * wb[(size_t)j * 20480 + base + il];  // lane-coalesced
    }
#pragma unroll
    for (int j = 0; j < 10; ++j) red[tid * 10 + j] = acc[j];
    __syncthreads();
    for (int off2 = 128; off2 > 0; off2 >>= 1) {
      if (tid < off2) {
#pragma unroll
        for (int j = 0; j < 10; ++j) red[tid * 10 + j] += red[(tid + off2) * 10 + j];
      }
      __syncthreads();
    }
    if (tid < 10) part2[((b << 4) + strip) * 10 + tid] = red[tid];
  }
}

// ---------------- phase 5: dense head (combine strips + dense2/3) ---------
__device__ __forceinline__ void dense_body(
    char* smemc, const int blk, const int tid,
    const float* __restrict__ part2, const float* __restrict__ B1,
    const float* __restrict__ W2, const float* __restrict__ B2,
    const float* __restrict__ W3, const float* __restrict__ B3,
    float* __restrict__ out) {
  if (blk >= 64) return;
  float* y1 = (float*)smemc;
  float* y2 = y1 + 16;
  const int b = blk;
  if (tid < 10) {
    int j = tid;
    float s = 0.f;
#pragma unroll
    for (int st = 0; st < 16; ++st) s += part2[((b << 4) + st) * 10 + j];
    y1[j] = s + B1[j];
  }
  __syncthreads();
  if (tid < 10) {
    int j = tid;
    float s = B2[j];
#pragma unroll
    for (int i = 0; i < 10; ++i) s += y1[i] * W2[i * 10 + j];
    y2[j] = s;
  }
  __syncthreads();
  if (tid < 10) {
    int j = tid;
    float s = B3[j];
#pragma unroll
    for (int i = 0; i < 10; ++i) s += y2[i] * W3[i * 10 + j];
    out[b * 10 + j] = s;
  }
}

// ---------------- the cooperative mega-kernel -----------------------------
__global__ __launch_bounds__(256, 4) void mega_kernel(
    const int* inp, const float* cw1, const float* cb1, const float* cw2,
    const float* cb2, const float* cw3, const float* cb3,
    const float* a1K, const float* a1Q, const float* a1V,
    const float* a2K, const float* a2Q, const float* a2V,
    const float* a3K, const float* a3Q, const float* a3V,
    const float* dw1, const float* db1, const float* dw2, const float* db2,
    const float* dw3, const float* db3, float* outp,
    ushort_t* qbA, ushort_t* kbA, ushort_t* vtA,
    ushort_t* qbB, ushort_t* kbB, ushort_t* vtB,
    float* part2, float* w1t, float* c2) {
  cg::grid_group grid = cg::this_grid();
  __shared__ __align__(16) char smem[SMEM_BYTES];
  const int blk = blockIdx.x, tid = threadIdx.x;
  conv12_body(smem, blk, tid, gridDim.x, inp, cw1, cb1, cw2, cb2, c2, dw1, w1t);
  grid.sync();
  conv3proj_body(smem, blk, tid, c2, cw3, cb3, a1K, a1Q, a1V, qbA, kbA, vtA);
  grid.sync();
  attn_body<true>(smem, blk, tid, qbA, kbA, vtA, a2K, a2Q, a2V,
                  qbB, kbB, vtB, nullptr, nullptr);
  grid.sync();
  attn_body<true>(smem, blk, tid, qbB, kbB, vtB, a3K, a3Q, a3V,
                  qbA, kbA, vtA, nullptr, nullptr);
  grid.sync();
  attn_body<false>(smem, blk, tid, qbA, kbA, vtA, nullptr, nullptr, nullptr,
                   nullptr, nullptr, nullptr, w1t, part2);
  grid.sync();
  dense_body(smem, blk, tid, part2, db1, dw2, db2, dw3, db3, outp);
}

// ---------------- fallback wrappers (plain 6-launch path) -----------------
__global__ __launch_bounds__(256) void conv12_kernel(
    const int* inp, const float* W1c, const float* B1c, const float* W2c,
    const float* B2c, float* out, const float* W1d, float* W1T) {
  __shared__ __align__(16) char smem[2048];
  conv12_body(smem, blockIdx.x, threadIdx.x, gridDim.x,
              inp, W1c, B1c, W2c, B2c, out, W1d, W1T);
}
__global__ __launch_bounds__(256) void conv3_proj_kernel(
    const float* in, const float* W, const float* Bi, const float* Kw,
    const float* Qw, const float* Vw, ushort_t* Qb, ushort_t* Kb, ushort_t* Vt) {
  __shared__ __align__(16) char smem[6464];
  conv3proj_body(smem, blockIdx.x, threadIdx.x, in, W, Bi, Kw, Qw, Vw, Qb, Kb, Vt);
}
template <bool FUSE>
__global__ __launch_bounds__(256) void attn_kernel(
    const ushort_t* Qb, const ushort_t* Kb, const ushort_t* Vt,
    const float* Kw2, const float* Qw2, const float* Vw2,
    ushort_t* Qb2, ushort_t* Kb2, ushort_t* Vt2,
    const float* W1T, float* part2) {
  __shared__ __align__(16) char smem[SMEM_BYTES];
  attn_body<FUSE>(smem, blockIdx.x, threadIdx.x, Qb, Kb, Vt, Kw2, Qw2, Vw2,
                  Qb2, Kb2, Vt2, W1T, part2);
}
__global__ __launch_bounds__(256) void dense_final(
    const float* part2, const float* B1, const float* W2, const float* B2,
    const float* W3, const float* B3, float* out) {
  __shared__ __align__(16) char smem[128];
  dense_body(smem, blockIdx.x, threadIdx.x, part2, B1, W2, B2, W3, B3, out);
}

extern "C" void kernel_launch(void* const* d_in, const int* in_sizes, int n_in,
                              void* d_out, int out_size, void* d_ws, size_t ws_size,
                              hipStream_t stream) {
  const int*   inp = (const int*)d_in[0];
  const float* cw1 = (const float*)d_in[1];
  const float* cb1 = (const float*)d_in[2];
  const float* cw2 = (const float*)d_in[3];
  const float* cb2 = (const float*)d_in[4];
  const float* cw3 = (const float*)d_in[5];
  const float* cb3 = (const float*)d_in[6];
  const float* a1K = (const float*)d_in[7];
  const float* a1Q = (const float*)d_in[8];
  const float* a1V = (const float*)d_in[9];
  const float* a2K = (const float*)d_in[10];
  const float* a2Q = (const float*)d_in[11];
  const float* a2V = (const float*)d_in[12];
  const float* a3K = (const float*)d_in[13];
  const float* a3Q = (const float*)d_in[14];
  const float* a3V = (const float*)d_in[15];
  const float* dw1 = (const float*)d_in[16];
  const float* db1 = (const float*)d_in[17];
  const float* dw2 = (const float*)d_in[18];
  const float* db2 = (const float*)d_in[19];
  const float* dw3 = (const float*)d_in[20];
  const float* db3 = (const float*)d_in[21];
  float* outp = (float*)d_out;

  // workspace layout (float units) — same as R19
  float* wsf = (float*)d_ws;
  ushort_t* qbA  = (ushort_t*)(wsf);            // [65536][32] bf16
  ushort_t* kbA  = (ushort_t*)(wsf + 1048576);
  ushort_t* vtA  = (ushort_t*)(wsf + 2097152);  // [B,32,S]
  float*    part2= wsf + 4456448;               // [64,16,10]
  float*    w1t  = wsf + 4466688;               // [10,20480]
  ushort_t* qbB  = (ushort_t*)(wsf + 4671488);
  ushort_t* kbB  = (ushort_t*)(wsf + 5712384);  // B-buffers overlap dead c2
  ushort_t* vtB  = (ushort_t*)(wsf + 6760960);
  float*    c2   = wsf + 5242880;               // [B,4,2048,5]

  void* args[] = {
      (void*)&inp, (void*)&cw1, (void*)&cb1, (void*)&cw2, (void*)&cb2,
      (void*)&cw3, (void*)&cb3, (void*)&a1K, (void*)&a1Q, (void*)&a1V,
      (void*)&a2K, (void*)&a2Q, (void*)&a2V, (void*)&a3K, (void*)&a3Q,
      (void*)&a3V, (void*)&dw1, (void*)&db1, (void*)&dw2, (void*)&db2,
      (void*)&dw3, (void*)&db3, (void*)&outp, (void*)&qbA, (void*)&kbA,
      (void*)&vtA, (void*)&qbB, (void*)&kbB, (void*)&vtB, (void*)&part2,
      (void*)&w1t, (void*)&c2};
  hipError_t e = hipLaunchCooperativeKernel(
      (void*)mega_kernel, dim3(1024), dim3(256), args, 0, stream);
  if (e != hipSuccess) {
    (void)hipGetLastError();   // clear, use plain 6-launch fallback
    conv12_kernel<<<512, 256, 0, stream>>>(inp, cw1, cb1, cw2, cb2, c2, dw1, w1t);
    conv3_proj_kernel<<<256, 256, 0, stream>>>(c2, cw3, cb3, a1K, a1Q, a1V,
                                               qbA, kbA, vtA);
    attn_kernel<true><<<1024, 256, 0, stream>>>(
        qbA, kbA, vtA, a2K, a2Q, a2V, qbB, kbB, vtB, nullptr, nullptr);
    attn_kernel<true><<<1024, 256, 0, stream>>>(
        qbB, kbB, vtB, a3K, a3Q, a3V, qbA, kbA, vtA, nullptr, nullptr);
    attn_kernel<false><<<1024, 256, 0, stream>>>(
        qbA, kbA, vtA, nullptr, nullptr, nullptr, nullptr, nullptr, nullptr,
        w1t, part2);
    dense_final<<<64, 256, 0, stream>>>(part2, db1, dw2, db2, dw3, db3, outp);
  }
}

// Round 4
// 198.460 us; speedup vs baseline: 4.8624x; 4.8624x over previous
//
#include <hip/hip_runtime.h>
#include <hip/hip_bf16.h>

// Model: one_hot -> 3x Conv2D(5,(4,4),(1,2),SAME) -> [B,S=1024,D=20]
//        -> 3x causal self-attention -> flatten -> 3x Dense(10)
// B=64, L=8192, S=1024, D=20.
// R19 (215.5us): 6 launches, fused attn strips, balanced swizzle.
// R20 (267us): de-staged K+V -> latency-bound. R21 (228us): t-split into 10
//      launches -> gaps ~3us each, kernels dominate. R22 (965us): cooperative
//      mega-kernel -> grid.sync catastrophic. REVERTED.
// R23: R19 pipeline verbatim EXCEPT attn restructured for latency:
//      512-thr blocks, 8 waves = (q-subtile, t-half); V^T staged ONCE per
//      block (rows 0..19, 41KB) -> ZERO main-loop barriers (was 16); K read
//      direct from global (coalesced 1KB/wave, L1/L2-resident); per-wave
//      serial chain halved (<=32 chunks); wave-uniform skip of fully-masked
//      groups (thi = min(thi, qbase+16), -25% chunks); in-block half-merge
//      via LDS. LDS ~50KB -> 3 blocks/CU = 24 waves/CU (was 16).
//      __launch_bounds__(512,6) caps VGPR 85 (R19 used 68). Heavy strips
//      dispatched first (LPT); blk%8==b%8 keeps XCD b-locality.

#define B_ 64
#define L_ 8192
#define S_ 1024
#define D_ 20

typedef unsigned short ushort_t;
typedef __attribute__((ext_vector_type(8))) short short8_t;  // 8 bf16 (4 VGPRs)
typedef __attribute__((ext_vector_type(4))) short short4_t;  // 4 bf16 (2 VGPRs)
typedef __attribute__((ext_vector_type(4))) float f32x4_t;   // MFMA C/D

__device__ __forceinline__ ushort_t f2bf(float f) {          // RNE fp32->bf16
  unsigned u = __float_as_uint(f);
  return (ushort_t)((u + 0x7fffu + ((u >> 16) & 1u)) >> 16);
}
__device__ __forceinline__ float bf2f(ushort_t h) {
  return __uint_as_float(((unsigned)h) << 16);
}

// ---------------- fused conv1+conv2 (+ W1 transpose tail) ----------------
__global__ __launch_bounds__(256) void conv12_kernel(
    const int* __restrict__ inp,
    const float* __restrict__ W1c, const float* __restrict__ B1c,
    const float* __restrict__ W2c, const float* __restrict__ B2c,
    float* __restrict__ out,                      // c2 [B,4,2048,5]
    const float* __restrict__ W1d,                // dense W1 [20480,10]
    float* __restrict__ W1T) {                    // [10,20480]
  __shared__ float w1s[80], b1s[5], w2s[400], b2s[5];
  for (int j = threadIdx.x; j < 400; j += 256) w2s[j] = W2c[j];
  if (threadIdx.x < 80)      w1s[threadIdx.x]      = W1c[threadIdx.x];
  else if (threadIdx.x < 85) b1s[threadIdx.x - 80] = B1c[threadIdx.x - 80];
  else if (threadIdx.x < 90) b2s[threadIdx.x - 85] = B2c[threadIdx.x - 85];
  __syncthreads();
  const int idx = blockIdx.x * 256 + threadIdx.x;  // 131072 total
  const int b  = idx >> 11;
  const int wo = idx & 2047;
  const int* ib = inp + (size_t)b * L_;
  int iv[10];
#pragma unroll
  for (int t = 0; t < 10; ++t) {
    int g = 4 * wo - 3 + t;
    iv[t] = (g >= 0 && g < L_) ? ib[g] : -100;   // sentinel: no kh matches
  }
  float val[4][4][5];                            // [hi][pos][ci]
#pragma unroll
  for (int pos = 0; pos < 4; ++pos) {
    const int w1 = 2 * wo - 1 + pos;
    const bool okp = (w1 >= 0 && w1 < 4096);     // conv2 SAME padding -> 0
#pragma unroll
    for (int hi = 0; hi < 4; ++hi)
#pragma unroll
      for (int ci = 0; ci < 5; ++ci) val[hi][pos][ci] = okp ? b1s[ci] : 0.f;
    if (okp) {
#pragma unroll
      for (int kw = 0; kw < 4; ++kw) {
        const int gw = 2 * w1 - 1 + kw;
        if (gw >= 0 && gw < L_) {
          const int v = iv[2 * pos + kw];
#pragma unroll
          for (int hi = 0; hi < 4; ++hi) {
            const int kh = v - hi + 1;
            if (kh >= 0 && kh < 4) {
#pragma unroll
              for (int ci = 0; ci < 5; ++ci)
                val[hi][pos][ci] += w1s[(kh * 4 + kw) * 5 + ci];
            }
          }
        }
      }
    }
  }
  float acc[4][5];
#pragma unroll
  for (int h = 0; h < 4; ++h)
#pragma unroll
    for (int c = 0; c < 5; ++c) acc[h][c] = b2s[c];
#pragma unroll
  for (int kh = 0; kh < 4; ++kh)
#pragma unroll
    for (int kw = 0; kw < 4; ++kw)
#pragma unroll
      for (int ci = 0; ci < 5; ++ci) {
        const float* wp = w2s + ((kh * 4 + kw) * 5 + ci) * 5;
        float w0 = wp[0], w1v = wp[1], w2v = wp[2], w3 = wp[3], w4 = wp[4];
#pragma unroll
        for (int h = 0; h < 4; ++h) {
          int hi = h - 1 + kh;
          if (hi >= 0 && hi < 4) {
            float x = val[hi][kw][ci];
            acc[h][0] += w0 * x;  acc[h][1] += w1v * x; acc[h][2] += w2v * x;
            acc[h][3] += w3 * x;  acc[h][4] += w4 * x;
          }
        }
      }
  float* ob = out + (size_t)b * 4 * 2048 * 5;
#pragma unroll
  for (int h = 0; h < 4; ++h)
#pragma unroll
    for (int c = 0; c < 5; ++c) ob[(h * 2048 + wo) * 5 + c] = acc[h][c];
  // ---- tail: W1 transpose (grid-stride over 204800 elements) ----
  for (int j = idx; j < 204800; j += 131072) {
    int col = j / 20480, i2 = j - col * 20480;
    W1T[j] = W1d[i2 * 10 + col];
  }
}

// ---------------- fused conv3 + proj (layer 1) ----------------
__global__ __launch_bounds__(256) void conv3_proj_kernel(
    const float* __restrict__ in,                 // c2 [B,4,2048,5]
    const float* __restrict__ W,  const float* __restrict__ Bi,
    const float* __restrict__ Kw, const float* __restrict__ Qw,
    const float* __restrict__ Vw,
    ushort_t* __restrict__ Qb, ushort_t* __restrict__ Kb,
    ushort_t* __restrict__ Vt) {
  constexpr int WIN = 2048;
  __shared__ float ws[400], bs[5];
  __shared__ float kw[400], qw[400], vw[400];
  for (int j = threadIdx.x; j < 400; j += 256) {
    ws[j] = W[j]; kw[j] = Kw[j]; qw[j] = Qw[j]; vw[j] = Vw[j];
  }
  if (threadIdx.x < 5) bs[threadIdx.x] = Bi[threadIdx.x];
  __syncthreads();
  const int r  = blockIdx.x * 256 + threadIdx.x;  // row in [0, 65536)
  const int b  = r >> 10;
  const int wo = r & 1023;
  float val[4][4][5];
#pragma unroll
  for (int hi = 0; hi < 4; ++hi) {
    const float* ir = in + ((size_t)b * 4 + hi) * WIN * 5;
#pragma unroll
    for (int kwp = 0; kwp < 4; ++kwp) {
      int wi = 2 * wo - 1 + kwp;
      bool ok = (wi >= 0 && wi < WIN);
#pragma unroll
      for (int ci = 0; ci < 5; ++ci) val[hi][kwp][ci] = ok ? ir[wi * 5 + ci] : 0.f;
    }
  }
  float acc[4][5];
#pragma unroll
  for (int h = 0; h < 4; ++h)
#pragma unroll
    for (int c = 0; c < 5; ++c) acc[h][c] = bs[c];
#pragma unroll
  for (int kh = 0; kh < 4; ++kh)
#pragma unroll
    for (int kwp = 0; kwp < 4; ++kwp)
#pragma unroll
      for (int ci = 0; ci < 5; ++ci) {
        const float* wp = ws + ((kh * 4 + kwp) * 5 + ci) * 5;
        float w0 = wp[0], w1 = wp[1], w2 = wp[2], w3 = wp[3], w4 = wp[4];
#pragma unroll
        for (int h = 0; h < 4; ++h) {
          int hi = h - 1 + kh;
          if (hi >= 0 && hi < 4) {
            float x = val[hi][kwp][ci];
            acc[h][0] += w0 * x; acc[h][1] += w1 * x; acc[h][2] += w2 * x;
            acc[h][3] += w3 * x; acc[h][4] += w4 * x;
          }
        }
      }
  float x[D_];
#pragma unroll
  for (int h = 0; h < 4; ++h)
#pragma unroll
    for (int c = 0; c < 5; ++c) x[h * 5 + c] = acc[h][c];
  float q[D_], k[D_], v[D_];
#pragma unroll
  for (int j = 0; j < D_; ++j) { q[j] = 0.f; k[j] = 0.f; v[j] = 0.f; }
#pragma unroll
  for (int i = 0; i < D_; ++i) {
#pragma unroll
    for (int j = 0; j < D_; ++j) {
      q[j] += x[i] * qw[i * D_ + j];
      k[j] += x[i] * kw[i * D_ + j];
      v[j] += x[i] * vw[i * D_ + j];
    }
  }
  const float sc = 0.22360679774997896f;  // 1/sqrt(20)
  ushort_t qt[32], kt[32];
#pragma unroll
  for (int j = 0; j < D_; ++j) { qt[j] = f2bf(q[j] * sc); kt[j] = f2bf(k[j]); }
#pragma unroll
  for (int j = D_; j < 32; ++j) { qt[j] = 0; kt[j] = 0; }
  int4* qd = (int4*)(Qb + (size_t)r * 32);
  int4* kd = (int4*)(Kb + (size_t)r * 32);
#pragma unroll
  for (int j = 0; j < 4; ++j) {
    qd[j] = *(const int4*)(qt + 8 * j);
    kd[j] = *(const int4*)(kt + 8 * j);
  }
  ushort_t* vbase = Vt + ((size_t)b * 32) * 1024 + wo;
#pragma unroll
  for (int d = 0; d < D_; ++d) vbase[d * 1024] = f2bf(v[d]);
}

// ---------------- causal attention: 8 waves = (q-subtile, t-half) ---------
// S^T = mfma_16x16x32(Kfrag, Qfrag): lane (quad,n): S^T[t=quad*4+r][q=n].
// P^T register layout IS the B-operand of mfma_16x16x16; PV from registers.
// V^T rows 0..19 staged ONCE (stride 1032 us); K direct from global
// (16 rows x 64B contiguous per wave instr, L1/L2-hit). Zero main-loop
// barriers. Wave (sub=w&3, half=w>>2): q-subtile sub, t in [tlo,thi).
// Halves merged via LDS (mrg aliases ox region; mrgL for l).
// FUSE=true : epilogue projects O rows -> next layer's Qb2/Kb2/Vt2.
// FUSE=false: epilogue computes dense1 partial -> part2[b][strip][10].
template <bool FUSE>
__global__ __launch_bounds__(512, 6) void attn_kernel(
    const ushort_t* __restrict__ Qb, const ushort_t* __restrict__ Kb,
    const ushort_t* __restrict__ Vt,
    const float* __restrict__ Kw2, const float* __restrict__ Qw2,
    const float* __restrict__ Vw2,
    ushort_t* __restrict__ Qb2, ushort_t* __restrict__ Kb2,
    ushort_t* __restrict__ Vt2,
    const float* __restrict__ W1T,   // !FUSE: [10,20480]
    float* __restrict__ part2) {     // !FUSE: [64,16,10]
  constexpr int VST = 1032;                   // ushort stride (pad 8)
  __shared__ ushort_t vts[20 * VST];          // 41,280 B
  __shared__ float extraf[FUSE ? 2480 : 1280]; // FUSE: pw 1200 + ox 1280
  __shared__ float mrgL[64];                  // half1 l partials [sub][n]
  __shared__ float red2[FUSE ? 4 : 40];       // !FUSE: per-wave dense sums
  const int blk   = blockIdx.x;
  const int b     = blk & 63;                 // blk%8==b%8 -> XCD locality
  const int strip = 15 - (blk >> 6);          // heavy strips dispatch first
  const int q0    = strip * 64;
  const int nt    = q0 + 64;
  const int tid   = threadIdx.x;
  const int w     = tid >> 6;                 // wave 0..7
  const int sub   = w & 3;                    // q-subtile
  const int half  = w >> 2;                   // t-half
  const int lane  = tid & 63;
  const int n     = lane & 15;
  const int quad  = lane >> 4;
  const int qbase = q0 + 16 * sub;
  const int qg    = qbase + n;                // this lane's q column
  // ---- stage V^T rows 0..19, t < nt (once; no other barriers) ----
  const ushort_t* VtB = Vt + (size_t)b * 32 * 1024;
  const int ntc = nt >> 3;                    // 16B chunks per row
  for (int i = tid; i < 20 * ntc; i += 512) {
    int row = i / ntc, cc = i - row * ntc;
    *(int4*)(vts + row * VST + cc * 8) =
        *(const int4*)(VtB + (size_t)row * 1024 + cc * 8);
  }
  if (FUSE) {
    for (int j = tid; j < 1200; j += 512) {
      int m = j / 400, oo = j - m * 400;
      extraf[j] = (m == 0) ? Kw2[oo] : (m == 1) ? Qw2[oo] : Vw2[oo];
    }
  }
  const ushort_t* KbB = Kb + (size_t)b * 1024 * 32;
  short8_t qfrag = *(const short8_t*)(Qb + ((size_t)(b * 1024 + qbase + n)) * 32 + quad * 8);
  f32x4_t oA = {0.f, 0.f, 0.f, 0.f};          // O^T[d=quad*4+r][q=n]
  f32x4_t oB = {0.f, 0.f, 0.f, 0.f};          // O^T[d=16+quad*4+r][q=n] (quad0)
  const f32x4_t zero = {0.f, 0.f, 0.f, 0.f};
  float lsum = 0.f;
  const int nt2 = nt >> 1;
  const int tlo = half ? nt2 : 0;
  int thi = half ? nt : nt2;
  if (thi > qbase + 16) thi = qbase + 16;     // wave-uniform: skip all-masked
  __syncthreads();                            // vts (+pw) visible
  for (int t0 = tlo; t0 < thi; t0 += 32) {
    short8_t kf0 = *(const short8_t*)(KbB + (size_t)(t0 + n) * 32 + quad * 8);
    short8_t kf1 = *(const short8_t*)(KbB + (size_t)(t0 + 16 + n) * 32 + quad * 8);
#pragma unroll
    for (int c = 0; c < 2; ++c) {
      const int tg = t0 + c * 16 + quad * 4;  // global t of r=0
      f32x4_t s = __builtin_amdgcn_mfma_f32_16x16x32_bf16(c ? kf1 : kf0, qfrag,
                                                          zero, 0, 0, 0);
      ushort_t pk4[4];
#pragma unroll
      for (int r = 0; r < 4; ++r) {
        float p = (tg + r <= qg) ? __expf(s[r]) : 0.f;
        ushort_t h = f2bf(p);
        lsum += bf2f(h);                      // consistent with bf16 P in PV
        pk4[r] = h;
      }
      short4_t pfrag = *(const short4_t*)pk4; // B16-frag: k=quad*4+j, n=q
      short4_t vlo = *(const short4_t*)(vts + n * VST + t0 + c * 16 + quad * 4);
      short4_t vhi = *(const short4_t*)(vts + (16 + (n & 3)) * VST + t0 + c * 16 + quad * 4);
      oA = __builtin_amdgcn_mfma_f32_16x16x16bf16_1k(vlo, pfrag, oA, 0, 0, 0);
      oB = __builtin_amdgcn_mfma_f32_16x16x16bf16_1k(vhi, pfrag, oB, 0, 0, 0);
    }
  }
  // l[q=n]: reduce partial sums across the 4 quads
  float l = lsum;
  l += __shfl_xor(l, 16, 64);
  l += __shfl_xor(l, 32, 64);
  // ---- merge halves: half1 writes partials (ox layout), half0 adds ----
  float* ox  = FUSE ? (extraf + 1200) : extraf;   // [1280] = 4 x 320
  float* oxw = ox + sub * 320;
  if (half) {
#pragma unroll
    for (int r = 0; r < 4; ++r) oxw[n * 20 + quad * 4 + r] = oA[r];
    if (quad == 0) {
#pragma unroll
      for (int r = 0; r < 4; ++r) oxw[n * 20 + 16 + r] = oB[r];
      mrgL[sub * 16 + n] = l;
    }
  }
  __syncthreads();
  if (!half) {
#pragma unroll
    for (int r = 0; r < 4; ++r) oA[r] += oxw[n * 20 + quad * 4 + r];
    if (quad == 0) {
#pragma unroll
      for (int r = 0; r < 4; ++r) oB[r] += oxw[n * 20 + 16 + r];
    }
    l += mrgL[sub * 16 + n];                  // broadcast read per n
    const float inv = 1.f / l;
    // overwrite own region with normalized O (same addrs each lane read)
#pragma unroll
    for (int r = 0; r < 4; ++r) oxw[n * 20 + quad * 4 + r] = oA[r] * inv;
    if (quad == 0) {
#pragma unroll
      for (int r = 0; r < 4; ++r) oxw[n * 20 + 16 + r] = oB[r] * inv;
    }
  }
  if (FUSE) {
    if (!half) {
      float* pw = extraf;
      __asm__ volatile("s_waitcnt lgkmcnt(0)" ::: "memory");  // wave LDS RAW
      const int row  = lane >> 2;     // 0..15
      const int part = lane & 3;      // cols 5*part .. 5*part+4
      float x[D_];
#pragma unroll
      for (int i = 0; i < D_; ++i) x[i] = oxw[row * 20 + i];
      float qv[5], kv[5], vv[5];
#pragma unroll
      for (int jj = 0; jj < 5; ++jj) { qv[jj] = 0.f; kv[jj] = 0.f; vv[jj] = 0.f; }
#pragma unroll
      for (int i = 0; i < D_; ++i) {
        const float xi = x[i];
#pragma unroll
        for (int jj = 0; jj < 5; ++jj) {
          const int j = 5 * part + jj;
          kv[jj] += xi * pw[i * 20 + j];          // K block
          qv[jj] += xi * pw[400 + i * 20 + j];    // Q block
          vv[jj] += xi * pw[800 + i * 20 + j];    // V block
        }
      }
      const float sc = 0.22360679774997896f;
      const int rg = b * 1024 + qbase + row;
      const int s  = rg & 1023;
#pragma unroll
      for (int jj = 0; jj < 5; ++jj) {
        const int j = 5 * part + jj;
        Kb2[(size_t)rg * 32 + j] = f2bf(kv[jj]);
        Qb2[(size_t)rg * 32 + j] = f2bf(qv[jj] * sc);
        Vt2[(size_t)b * 32768 + (size_t)j * 1024 + s] = f2bf(vv[jj]);
      }
      if (part == 0) {
#pragma unroll
        for (int u = 0; u < 6; ++u)
          *(unsigned*)(Kb2 + (size_t)rg * 32 + 20 + 2 * u) = 0u;
      } else if (part == 1) {
#pragma unroll
        for (int u = 0; u < 6; ++u)
          *(unsigned*)(Qb2 + (size_t)rg * 32 + 20 + 2 * u) = 0u;
      }
    }
  } else {
    // ---- fused dense1 partial over this block's 64 rows ----
    __syncthreads();                     // normalized ox visible to all
    float acc[10];
#pragma unroll
    for (int j = 0; j < 10; ++j) acc[j] = 0.f;
    const int base = q0 * 20;
    if (tid < 256) {
#pragma unroll
      for (int k = 0; k < 5; ++k) {
        const int il = tid + 256 * k;
        const float xv = ox[il];
#pragma unroll
        for (int j = 0; j < 10; ++j)
          acc[j] += xv * W1T[(size_t)j * 20480 + base + il];  // lane-coalesced
      }
    }
    // wave butterfly reduce (tid>=256 contribute zeros)
#pragma unroll
    for (int off = 1; off < 64; off <<= 1) {
#pragma unroll
      for (int j = 0; j < 10; ++j) acc[j] += __shfl_xor(acc[j], off, 64);
    }
    if (tid < 256 && lane == 0) {
#pragma unroll
      for (int j = 0; j < 10; ++j) red2[w * 10 + j] = acc[j];
    }
    __syncthreads();
    if (tid < 10) {
      float s2 = red2[tid] + red2[10 + tid] + red2[20 + tid] + red2[30 + tid];
      part2[((b << 4) + strip) * 10 + tid] = s2;
    }
  }
}

// ---------------- dense head: combine strips + dense2/3 ----------------
__global__ __launch_bounds__(64) void dense_final(
    const float* __restrict__ part2,   // [64,16,10], strip-ordered
    const float* __restrict__ B1,
    const float* __restrict__ W2, const float* __restrict__ B2,
    const float* __restrict__ W3, const float* __restrict__ B3,
    float* __restrict__ out) {
  const int b = blockIdx.x;
  __shared__ float y1[10], y2[10];
  if (threadIdx.x < 10) {
    int j = threadIdx.x;
    float s = 0.f;
#pragma unroll
    for (int st = 0; st < 16; ++st) s += part2[((b << 4) + st) * 10 + j];
    y1[j] = s + B1[j];
  }
  __syncthreads();
  if (threadIdx.x < 10) {
    int j = threadIdx.x;
    float s = B2[j];
#pragma unroll
    for (int i = 0; i < 10; ++i) s += y1[i] * W2[i * 10 + j];
    y2[j] = s;
  }
  __syncthreads();
  if (threadIdx.x < 10) {
    int j = threadIdx.x;
    float s = B3[j];
#pragma unroll
    for (int i = 0; i < 10; ++i) s += y2[i] * W3[i * 10 + j];
    out[b * 10 + j] = s;
  }
}

extern "C" void kernel_launch(void* const* d_in, const int* in_sizes, int n_in,
                              void* d_out, int out_size, void* d_ws, size_t ws_size,
                              hipStream_t stream) {
  const int*   inp = (const int*)d_in[0];
  const float* cw1 = (const float*)d_in[1];
  const float* cb1 = (const float*)d_in[2];
  const float* cw2 = (const float*)d_in[3];
  const float* cb2 = (const float*)d_in[4];
  const float* cw3 = (const float*)d_in[5];
  const float* cb3 = (const float*)d_in[6];
  const float* a1K = (const float*)d_in[7];
  const float* a1Q = (const float*)d_in[8];
  const float* a1V = (const float*)d_in[9];
  const float* a2K = (const float*)d_in[10];
  const float* a2Q = (const float*)d_in[11];
  const float* a2V = (const float*)d_in[12];
  const float* a3K = (const float*)d_in[13];
  const float* a3Q = (const float*)d_in[14];
  const float* a3V = (const float*)d_in[15];
  const float* dw1 = (const float*)d_in[16];
  const float* db1 = (const float*)d_in[17];
  const float* dw2 = (const float*)d_in[18];
  const float* db2 = (const float*)d_in[19];
  const float* dw3 = (const float*)d_in[20];
  const float* db3 = (const float*)d_in[21];
  float* outp = (float*)d_out;

  // workspace layout (float units) — R19 verbatim
  float* wsf = (float*)d_ws;
  ushort_t* qbA  = (ushort_t*)(wsf);            // [65536][32] bf16  [0 .. 1,048,576)
  ushort_t* kbA  = (ushort_t*)(wsf + 1048576);  //                   [1,048,576 .. 2,097,152)
  ushort_t* vtA  = (ushort_t*)(wsf + 2097152);  // [B,32,S]          [2,097,152 .. 3,145,728)
  float*    part2= wsf + 4456448;               // [64,16,10]        [4,456,448 .. 4,466,688)
  float*    w1t  = wsf + 4466688;               // [10,20480]        ends 4,671,488
  ushort_t* qbB  = (ushort_t*)(wsf + 4671488);  // ends 5,195,776
  ushort_t* kbB  = (ushort_t*)(wsf + 5712384);  // B-buffers overlap dead c2 region
  ushort_t* vtB  = (ushort_t*)(wsf + 6760960);  //   (c2 consumed before attn1 writes B)
  float*    c2   = wsf + 5242880;               // [B,4,2048,5]      [5,242,880 .. 7,864,320)

  conv12_kernel<<<512, 256, 0, stream>>>(inp, cw1, cb1, cw2, cb2, c2, dw1, w1t);

  conv3_proj_kernel<<<256, 256, 0, stream>>>(c2, cw3, cb3, a1K, a1Q, a1V, qbA, kbA, vtA);
  // attn1: reads A, fused proj(layer2) -> B
  attn_kernel<true><<<1024, 512, 0, stream>>>(
      qbA, kbA, vtA, a2K, a2Q, a2V, qbB, kbB, vtB, nullptr, nullptr);
  // attn2: reads B, fused proj(layer3) -> A
  attn_kernel<true><<<1024, 512, 0, stream>>>(
      qbB, kbB, vtB, a3K, a3Q, a3V, qbA, kbA, vtA, nullptr, nullptr);
  // attn3: reads A, fused dense1 partial -> part2
  attn_kernel<false><<<1024, 512, 0, stream>>>(
      qbA, kbA, vtA, nullptr, nullptr, nullptr, nullptr, nullptr, nullptr,
      w1t, part2);

  dense_final<<<64, 64, 0, stream>>>(part2, db1, dw2, db2, dw3, db3, outp);
}